// Round 5
// baseline (497.929 us; speedup 1.0000x reference)
//
#include <hip/hip_runtime.h>
#include <cstdint>
#include <cstddef>

// ---------------------------------------------------------------------------
// GraphAttentionHead: out = elu(softmax(mask(LeakyReLU(mu_i + xi_j))) @ h)
// Round 5: barrier-light window-staged attention.
//   - exp-free weights: exp(LR(mu+xi)) = max(Emu*Exi, Fmu*Fxi), precomputed
//   - A-frags built in registers by consuming wave (i-split waves, no dup)
//   - B + bitmask + E/F staged per 256-j window (2 barriers/window, 8/block)
//   - Z via ones-column MFMA; partials to plain buffers (no atomics)
// ---------------------------------------------------------------------------

#define LOG2E 1.44269504f

typedef __attribute__((ext_vector_type(8))) short short8;   // 8 bf16 = 4 VGPRs
typedef __attribute__((ext_vector_type(4))) float floatx4;  // MFMA acc

using uint_as1 = __attribute__((address_space(1))) unsigned int;
using uint_as3 = __attribute__((address_space(3))) unsigned int;

__device__ __forceinline__ void gld_lds16(const void* g, void* l) {
  __builtin_amdgcn_global_load_lds((const uint_as1*)g, (uint_as3*)l, 16, 0, 0);
}

__device__ __forceinline__ unsigned short f2b(float f) {  // fp32 -> bf16 RNE (finite)
  unsigned u = __float_as_uint(f);
  u += 0x7fffu + ((u >> 16) & 1u);
  return (unsigned short)(u >> 16);
}
__device__ __forceinline__ float b2f(short s) {
  return __uint_as_float(((unsigned)(unsigned short)s) << 16);
}

// ------------------- K_bm: adj int32 [8192x8192] -> bitmask ----------------
__global__ void k_bitmask(const int* __restrict__ adj, unsigned long long* __restrict__ bm) {
  int gw = (blockIdx.x * 256 + threadIdx.x) >> 6;
  int lane = threadIdx.x & 63;
  size_t w0 = (size_t)gw * 128;
  for (int r = 0; r < 128; r += 4) {
    size_t wd = w0 + r;
    int v0 = adj[(wd + 0) * 64 + lane];
    int v1 = adj[(wd + 1) * 64 + lane];
    int v2 = adj[(wd + 2) * 64 + lane];
    int v3 = adj[(wd + 3) * 64 + lane];
    unsigned long long m0 = __ballot(v0 != 0);
    unsigned long long m1 = __ballot(v1 != 0);
    unsigned long long m2 = __ballot(v2 != 0);
    unsigned long long m3 = __ballot(v3 != 0);
    if (lane == 0) {
      bm[wd] = m0; bm[wd + 1] = m1; bm[wd + 2] = m2; bm[wd + 3] = m3;
    }
  }
}

// --------------------------- K0a: features -> bf16 -------------------------
__global__ void k_cvt_features(const float* __restrict__ f, unsigned short* __restrict__ fb) {
  int tid = blockIdx.x * 256 + threadIdx.x;
  float4 v = ((const float4*)f)[tid];
  ushort4 o = {f2b(v.x), f2b(v.y), f2b(v.z), f2b(v.w)};
  *(ushort4*)&fb[tid * 4] = o;
}

// ------------------- K0b: W_phi [512][256] -> Wt bf16 [256][512] ------------
__global__ void k_prep_wt(const float* __restrict__ w, unsigned short* __restrict__ wt) {
  int tid = blockIdx.x * 256 + threadIdx.x;
  int n = tid >> 9, k = tid & 511;
  wt[n * 512 + k] = f2b(w[k * 256 + n]);
}

// ----------------- K0c: p_mu = W_phi @ w_mu, p_xi = W_phi @ w_xi ------------
__global__ void k_prep_p(const float* __restrict__ w, const float* __restrict__ wmu,
                         const float* __restrict__ wxi, float* __restrict__ pmu,
                         float* __restrict__ pxi) {
  int tid = blockIdx.x * 256 + threadIdx.x;
  int k = tid >> 2, seg = tid & 3;
  float sm = 0.f, sx = 0.f;
  int base = k * 256 + seg * 64;
#pragma unroll
  for (int c = 0; c < 64; c += 4) {
    float4 wv = *(const float4*)&w[base + c];
    float4 mv = *(const float4*)&wmu[seg * 64 + c];
    float4 xv = *(const float4*)&wxi[seg * 64 + c];
    sm += wv.x * mv.x + wv.y * mv.y + wv.z * mv.z + wv.w * mv.w;
    sx += wv.x * xv.x + wv.y * xv.y + wv.z * xv.z + wv.w * xv.w;
  }
  sm += __shfl_xor(sm, 1); sm += __shfl_xor(sm, 2);
  sx += __shfl_xor(sx, 1); sx += __shfl_xor(sx, 2);
  if (seg == 0) { pmu[k] = sm; pxi[k] = sx; }
}

// --- K2: mu/xi matvec, then store Emu=e^mu, Fmu=e^0.2mu, Exi, Fxi -----------
__global__ void k_mu_xi(const unsigned short* __restrict__ fb, const float* __restrict__ pmu,
                        const float* __restrict__ pxi, float* __restrict__ Emu,
                        float* __restrict__ Fmu, float* __restrict__ Exi,
                        float* __restrict__ Fxi) {
  int w = threadIdx.x >> 6, l = threadIdx.x & 63;
  int i = blockIdx.x * 4 + w;
  short8 fv = *(const short8*)&fb[i * 512 + l * 8];
  float m = 0.f, x = 0.f;
#pragma unroll
  for (int c = 0; c < 8; ++c) {
    float fvf = b2f(fv[c]);
    m = fmaf(fvf, pmu[l * 8 + c], m);
    x = fmaf(fvf, pxi[l * 8 + c], x);
  }
#pragma unroll
  for (int off = 32; off > 0; off >>= 1) {
    m += __shfl_xor(m, off);
    x += __shfl_xor(x, off);
  }
  if (l == 0) {
    float ms = m * LOG2E, xs = x * LOG2E;
    Emu[i] = __builtin_amdgcn_exp2f(ms);
    Fmu[i] = __builtin_amdgcn_exp2f(0.2f * ms);
    Exi[i] = __builtin_amdgcn_exp2f(xs);
    Fxi[i] = __builtin_amdgcn_exp2f(0.2f * xs);
  }
}

// ------------- K1: h_t[n][m] = (features @ W_phi)^T, bf16 MFMA --------------
__global__ __launch_bounds__(256, 2) void k_gemm1(const unsigned short* __restrict__ fb,
                                                  const unsigned short* __restrict__ wt,
                                                  unsigned short* __restrict__ ht) {
  __shared__ __align__(16) unsigned short As[64 * 64];
  __shared__ __align__(16) unsigned short Bs[128 * 64];
  int t = threadIdx.x, w = t >> 6, l = t & 63;
  int bm_ = blockIdx.x >> 1, bn = blockIdx.x & 1;
  int m0 = bm_ * 64, n0 = bn * 128;
  int lr = l >> 3, lg = l & 7, g = lg ^ lr;
  int kg = l >> 4, ln = l & 15;
  floatx4 zero = {0.f, 0.f, 0.f, 0.f};
  floatx4 acc[4][2];
#pragma unroll
  for (int mf = 0; mf < 4; ++mf)
#pragma unroll
    for (int nf = 0; nf < 2; ++nf) acc[mf][nf] = zero;

  for (int it = 0; it < 8; ++it) {
    int k0 = it * 64;
#pragma unroll
    for (int q = 0; q < 2; ++q) {
      int row = w * 16 + q * 8 + lr;
      const void* gp = fb + (size_t)(m0 + row) * 512 + k0 + g * 8;
      int lb = __builtin_amdgcn_readfirstlane((w * 16 + q * 8) * 64);
      gld_lds16(gp, &As[lb]);
    }
#pragma unroll
    for (int q = 0; q < 4; ++q) {
      int row = w * 32 + q * 8 + lr;
      const void* gp = wt + (size_t)(n0 + row) * 512 + k0 + g * 8;
      int lb = __builtin_amdgcn_readfirstlane((w * 32 + q * 8) * 64);
      gld_lds16(gp, &Bs[lb]);
    }
    __syncthreads();
#pragma unroll
    for (int ks = 0; ks < 2; ++ks) {
      int gg = ks * 4 + kg;
      int swz = (gg ^ (ln & 7)) * 8;
      short8 bfr[2];
#pragma unroll
      for (int nf = 0; nf < 2; ++nf)
        bfr[nf] = *(const short8*)&Bs[(w * 32 + nf * 16 + ln) * 64 + swz];
#pragma unroll
      for (int mf = 0; mf < 4; ++mf) {
        short8 afr = *(const short8*)&As[(mf * 16 + ln) * 64 + swz];
#pragma unroll
        for (int nf = 0; nf < 2; ++nf)
          acc[mf][nf] = __builtin_amdgcn_mfma_f32_16x16x32_bf16(afr, bfr[nf], acc[mf][nf], 0, 0, 0);
      }
    }
    __syncthreads();
  }
#pragma unroll
  for (int mf = 0; mf < 4; ++mf)
#pragma unroll
    for (int nf = 0; nf < 2; ++nf) {
      int ng = n0 + w * 32 + nf * 16 + ln;
      int mg = m0 + mf * 16 + kg * 4;
      ushort4 o = {f2b(acc[mf][nf][0]), f2b(acc[mf][nf][1]),
                   f2b(acc[mf][nf][2]), f2b(acc[mf][nf][3])};
      *(ushort4*)&ht[(size_t)ng * 8192 + mg] = o;
    }
}

// --------------------- K3: window-staged masked attention -------------------
// grid 512 = 32 ibl x 2 nbl x 8 jbl. Block 256i x 128n x 1024j; 4 waves
// i-split (wave 64i x 128n, acc 4x8 frags). 4 windows of 256j; per window:
// stage B(64KB)+bits(8KB)+E/F(2KB), 2 barriers, then 8 barrier-free k-steps.
__global__ __launch_bounds__(256, 2) void k_attn6(const unsigned char* __restrict__ bm8,
                                                  const unsigned short* __restrict__ ht,
                                                  const float* __restrict__ Emu,
                                                  const float* __restrict__ Fmu,
                                                  const float* __restrict__ Exi,
                                                  const float* __restrict__ Fxi,
                                                  float* __restrict__ nump,
                                                  float* __restrict__ zpart) {
  __shared__ __align__(16) unsigned short Bs[128 * 256];  // [n][j] swizzled, 64 KB
  __shared__ __align__(16) unsigned char BitS[256 * 32];  // [i][j/8], 8 KB
  __shared__ __align__(16) float ExiS[256];               // window Exi slice
  __shared__ __align__(16) float FxiS[256];

  int t = threadIdx.x, w = t >> 6, l = t & 63;
  int ln = l & 15, kg = l >> 4;
  int b = blockIdx.x;
  int ib = b & 31, nb = (b >> 5) & 1, jb = b >> 6;
  int i0 = ib * 256, n0 = nb * 128;
  int jbase = jb * 1024;

  // per-thread row constants (wave covers i0 + w*64 .. +64)
  float emu[4], fmu[4];
#pragma unroll
  for (int mf = 0; mf < 4; ++mf) {
    int i = i0 + w * 64 + mf * 16 + ln;
    emu[mf] = Emu[i];
    fmu[mf] = Fmu[i];
  }

  floatx4 zero = {0.f, 0.f, 0.f, 0.f};
  floatx4 acc[4][8];
#pragma unroll
  for (int mf = 0; mf < 4; ++mf)
#pragma unroll
    for (int nf = 0; nf < 8; ++nf) acc[mf][nf] = zero;
  floatx4 accz[4];
#pragma unroll
  for (int mf = 0; mf < 4; ++mf) accz[mf] = zero;

  short8 ones;
#pragma unroll
  for (int e = 0; e < 8; ++e) ones[e] = (short)0x3F80;  // bf16 1.0

  for (int win = 0; win < 4; ++win) {
    int jcol = jbase + win * 256;
    __syncthreads();  // prior window's LDS reads complete
    // --- stage B: wave w -> rows [w*32, w*32+32), 16 loads of 1KB ---
#pragma unroll
    for (int q = 0; q < 16; ++q) {
      int r0 = w * 32 + q * 2;
      int rowl = r0 + (l >> 5);
      int glog = (l & 31) ^ (rowl & 7);
      const void* gp = ht + (size_t)(n0 + rowl) * 8192 + jcol + glog * 8;
      int lb = __builtin_amdgcn_readfirstlane(r0 * 256);
      gld_lds16(gp, &Bs[lb]);
    }
    // --- stage bits: wave w -> rows [w*64, w*64+64), 2 loads ---
#pragma unroll
    for (int q2 = 0; q2 < 2; ++q2) {
      int r0 = w * 64 + q2 * 32;
      int row = r0 + (l >> 1);
      const void* gp = bm8 + (size_t)(i0 + row) * 1024 + (jcol >> 3) + (l & 1) * 16;
      int lb = __builtin_amdgcn_readfirstlane(r0 * 32);
      gld_lds16(gp, &BitS[lb]);
    }
    // --- stage Exi/Fxi slices (waves 2,3) ---
    if (w == 2) gld_lds16(Exi + jcol + l * 4, &ExiS[0]);
    if (w == 3) gld_lds16(Fxi + jcol + l * 4, &FxiS[0]);
    __syncthreads();  // staging drained

    // --- 8 barrier-free k-steps over the window ---
#pragma unroll
    for (int ks = 0; ks < 8; ++ks) {
      int gran = ks * 4 + kg;            // 16B granule idx in window (0..31)
      int jo = gran * 8;                 // window-local j of this lane's 8 elems
      float4 e0 = *(const float4*)&ExiS[jo];
      float4 e1 = *(const float4*)&ExiS[jo + 4];
      float4 f0 = *(const float4*)&FxiS[jo];
      float4 f1 = *(const float4*)&FxiS[jo + 4];
      float ex[8] = {e0.x, e0.y, e0.z, e0.w, e1.x, e1.y, e1.z, e1.w};
      float fx[8] = {f0.x, f0.y, f0.z, f0.w, f1.x, f1.y, f1.z, f1.w};
      short8 af[4];
#pragma unroll
      for (int mf = 0; mf < 4; ++mf) {
        unsigned bits = BitS[(w * 64 + mf * 16 + ln) * 32 + gran];
        float A = emu[mf], F = fmu[mf];
#pragma unroll
        for (int e = 0; e < 8; ++e) {
          float wv = fmaxf(A * ex[e], F * fx[e]);
          wv = (bits & (1u << e)) ? wv : 0.f;
          af[mf][e] = (short)f2b(wv);
        }
      }
#pragma unroll
      for (int mf = 0; mf < 4; ++mf)  // Z via ones-column MFMA
        accz[mf] = __builtin_amdgcn_mfma_f32_16x16x32_bf16(af[mf], ones, accz[mf], 0, 0, 0);
#pragma unroll
      for (int nf = 0; nf < 8; ++nf) {
        int nl = nf * 16 + ln;
        short8 bf = *(const short8*)&Bs[nl * 256 + ((gran ^ (nl & 7)) * 8)];
#pragma unroll
        for (int mf = 0; mf < 4; ++mf)
          acc[mf][nf] = __builtin_amdgcn_mfma_f32_16x16x32_bf16(af[mf], bf, acc[mf][nf], 0, 0, 0);
      }
    }
  }

  // ---- epilogue: numerator partial (plain stores) + Z partial ----
  float* np = nump + (size_t)jb * (8192 * 256);
#pragma unroll
  for (int mf = 0; mf < 4; ++mf) {
    int rowb = i0 + w * 64 + mf * 16 + kg * 4;
#pragma unroll
    for (int nf = 0; nf < 8; ++nf) {
      int col = n0 + nf * 16 + ln;
#pragma unroll
      for (int r = 0; r < 4; ++r)
        np[(size_t)(rowb + r) * 256 + col] = acc[mf][nf][r];
    }
    if (nb == 0 && ln == 0) {
#pragma unroll
      for (int r = 0; r < 4; ++r)
        zpart[jb * 8192 + rowb + r] = accz[mf][r];
    }
  }
}

// ---------------- K4: finalize: sum partials, /Z, ELU -----------------------
__global__ void k_final(const float* __restrict__ nump, const float* __restrict__ zpart,
                        float* __restrict__ out) {
  int tid = blockIdx.x * 256 + threadIdx.x;  // x4 floats
  int i = tid >> 6;
  float z = 0.f;
#pragma unroll
  for (int p = 0; p < 8; ++p) z += zpart[p * 8192 + i];
  float zi = 1.0f / z;
  float4 v = {0.f, 0.f, 0.f, 0.f};
#pragma unroll
  for (int p = 0; p < 8; ++p) {
    float4 s = *(const float4*)&nump[(size_t)p * (8192 * 256) + tid * 4];
    v.x += s.x; v.y += s.y; v.z += s.z; v.w += s.w;
  }
  v.x *= zi; v.y *= zi; v.z *= zi; v.w *= zi;
  v.x = (v.x > 0.f) ? v.x : (__builtin_amdgcn_exp2f(v.x * LOG2E) - 1.f);
  v.y = (v.y > 0.f) ? v.y : (__builtin_amdgcn_exp2f(v.y * LOG2E) - 1.f);
  v.z = (v.z > 0.f) ? v.z : (__builtin_amdgcn_exp2f(v.z * LOG2E) - 1.f);
  v.w = (v.w > 0.f) ? v.w : (__builtin_amdgcn_exp2f(v.w * LOG2E) - 1.f);
  *(float4*)&out[tid * 4] = v;
}

// ---------------------------------------------------------------------------
extern "C" void kernel_launch(void* const* d_in, const int* in_sizes, int n_in,
                              void* d_out, int out_size, void* d_ws, size_t ws_size,
                              hipStream_t stream) {
  const float* features = (const float*)d_in[0];
  const int* adjm = (const int*)d_in[1];
  const float* W_phi = (const float*)d_in[2];
  const float* w_mu = (const float*)d_in[3];
  const float* w_xi = (const float*)d_in[4];
  float* out = (float*)d_out;

  char* ws = (char*)d_ws;
  unsigned short* fb  = (unsigned short*)(ws + 0);         // 8192x512 bf16 = 8 MB
  unsigned short* ht  = (unsigned short*)(ws + 8388608);   // 256x8192 bf16 = 4 MB
  unsigned short* wt  = (unsigned short*)(ws + 12582912);  // 256x512 bf16 = 256 KB
  float* pmu = (float*)(ws + 12845056);                    // 512 f32
  float* pxi = (float*)(ws + 12847104);                    // 512 f32
  float* Emu = (float*)(ws + 12849152);                    // 8192 f32
  float* Fmu = (float*)(ws + 12881920);
  float* Exi = (float*)(ws + 12914688);
  float* Fxi = (float*)(ws + 12947456);
  unsigned char* bmask = (unsigned char*)(ws + 13631488);  // 8 MB bitmask
  float* zpart = (float*)(ws + 22020096);                  // 8 x 8192 f32 = 256 KB
  float* nump  = (float*)(ws + 25165824);                  // 8 x 8 MB partials

  k_bitmask<<<2048, 256, 0, stream>>>(adjm, (unsigned long long*)bmask);
  k_cvt_features<<<4096, 256, 0, stream>>>(features, fb);
  k_prep_wt<<<512, 256, 0, stream>>>(W_phi, wt);
  k_prep_p<<<8, 256, 0, stream>>>(W_phi, w_mu, w_xi, pmu, pxi);
  k_mu_xi<<<2048, 256, 0, stream>>>(fb, pmu, pxi, Emu, Fmu, Exi, Fxi);
  k_gemm1<<<256, 256, 0, stream>>>(fb, wt, ht);
  k_attn6<<<512, 256, 0, stream>>>(bmask, ht, Emu, Fmu, Exi, Fxi, nump, zpart);
  k_final<<<2048, 256, 0, stream>>>(nump, zpart, out);
}